// Round 6
// baseline (1753.901 us; speedup 1.0000x reference)
//
#include <hip/hip_runtime.h>
#include <hip/hip_bf16.h>
#include <math.h>

// ---------------------------------------------------------------------------
// CART soft-decision-tree fused pipeline — round 6: GEMM1 on MFMA bf16-split.
//   out[b,o] = (1/T) sum_t relu(sigmoid(xn@P_t - cut_t) @ W1_t + b1_t) @ W2_t * tw_t + bias
// Folds: BN affine into projection A[f,ts] (stored split bf16, transposed),
//        cut into c2[ts], tw/T into W2eff, b2*tw/T into bias_out.
// GEMM1: x (fp32, split in-kernel to bf16 hi/lo) @ A (bf16 hi/lo) via
//        mfma_f32_16x16x32_bf16, 3 products (hi*hi + lo*hi + hi*lo).
// MLP (sigmoid/GEMM2/relu/GEMM3) stays fp32 VALU, weights transposed in LDS.
// ---------------------------------------------------------------------------

#define B_ROWS 65536
#define F_DIM  256
#define T_TREES 32
#define NC     1024
#define BN_EPS 1e-5f

// ws layout (float offsets)
#define WS_SUM    0
#define WS_SUMSQ  256
#define WS_SCALE  512
#define WS_SHIFT  768
#define WS_BIAS   1024        // 16
#define WS_C2     1040        // 1024
#define WS_AHT    2560        // A^T hi: [1024 cols][256 f] bf16 = 131072 floats
#define WS_ALT    133632      // A^T lo: same size
#define WS_PART   264704      // 8 * 65536*16
#define WS_FLOATS_ATOMIC  264704
#define WS_FLOATS_PARTIAL (264704 + 8*1048576)

typedef __attribute__((ext_vector_type(8))) short bf16x8;   // 4 VGPRs (A/B frag)
typedef __attribute__((ext_vector_type(4))) float f32x4;    // C/D frag

// Truncate-split: v = hi + lo with |err| ~ 2^-17 |v| after both products.
__device__ __forceinline__ void split_bf16(float v, unsigned short& h, unsigned short& l) {
    unsigned u = __builtin_bit_cast(unsigned, v);
    h = (unsigned short)(u >> 16);
    float hf = __builtin_bit_cast(float, (unsigned)h << 16);
    float lo = v - hf;                       // exact (Sterbenz)
    l = (unsigned short)(__builtin_bit_cast(unsigned, lo) >> 16);
}

__global__ void k_zero(float* ws) {
    ws[threadIdx.x] = 0.0f;   // zeros WS_SUM + WS_SUMSQ, block=512
}

__global__ void k_stats(const float* __restrict__ x, float* __restrict__ ws) {
    const int f  = threadIdx.x;
    const int r0 = blockIdx.x * 128;
    float s = 0.f, sq = 0.f;
    const float* p = x + (size_t)r0 * F_DIM + f;
#pragma unroll 4
    for (int r = 0; r < 128; ++r) { float v = p[(size_t)r * F_DIM]; s += v; sq += v * v; }
    atomicAdd(&ws[WS_SUM  + f], s);
    atomicAdd(&ws[WS_SUMSQ + f], sq);
}

__global__ void k_finalize(const float* __restrict__ gamma, const float* __restrict__ beta,
                           const float* __restrict__ b2, const float* __restrict__ tw,
                           float* __restrict__ ws) {
    const int f = threadIdx.x;
    const float inv = 1.0f / (float)B_ROWS;
    float mean = ws[WS_SUM + f] * inv;
    float var  = ws[WS_SUMSQ + f] * inv - mean * mean;
    float sc   = gamma[f] / sqrtf(var + BN_EPS);
    ws[WS_SCALE + f] = sc;
    ws[WS_SHIFT + f] = beta[f] - mean * sc;
    if (f < 16) {
        float acc = 0.f;
        for (int t = 0; t < T_TREES; ++t) acc += b2[t * 16 + f] * tw[t * 16 + f];
        ws[WS_BIAS + f] = acc * (1.0f / (float)T_TREES);
    }
}

// One block per (t,s) column. Emits AhT/AlT[col][f] (bf16 split of scale*P)
// and c2[col] = sum_f shift[f]*P[f] - cut[col].
__global__ void k_sparsemax(const float* __restrict__ fsm, const float* __restrict__ cut,
                            float* __restrict__ ws) {
    __shared__ float zs[256];
    __shared__ float zo[256];
    __shared__ float csA[256];
    __shared__ float csB[256];
    __shared__ float red[256];
    __shared__ int   redi[256];
    const int tid = threadIdx.x;
    const int col = blockIdx.x;           // t*32 + s
    const int t = col >> 5, s = col & 31;
    const float z = fsm[t * 8192 + tid * 32 + s];
    zo[tid] = z;
    zs[tid] = z;
    for (int size = 2; size <= 256; size <<= 1) {
        for (int stride = size >> 1; stride > 0; stride >>= 1) {
            __syncthreads();
            const int p = tid ^ stride;
            const float a = zs[tid], b = zs[p];
            __syncthreads();
            const bool up    = ((tid & size) == 0);
            const bool lower = ((tid & stride) == 0);
            zs[tid] = (lower == up) ? fminf(a, b) : fmaxf(a, b);
        }
    }
    __syncthreads();
    csA[tid] = zs[255 - tid];
    __syncthreads();
    float* src = csA; float* dst = csB;
    for (int off = 1; off < 256; off <<= 1) {
        float v = src[tid];
        if (tid >= off) v += src[tid - off];
        dst[tid] = v;
        __syncthreads();
        float* tmp = src; src = dst; dst = tmp;
    }
    const float zd = zs[255 - tid];
    const float kk = (float)(tid + 1);
    redi[tid] = (1.0f + kk * zd > src[tid]) ? 1 : 0;
    __syncthreads();
    for (int off = 128; off > 0; off >>= 1) {
        if (tid < off) redi[tid] += redi[tid + off];
        __syncthreads();
    }
    const int ksup = redi[0];
    const float tau = (src[ksup - 1] - 1.0f) / (float)ksup;
    const float P = fmaxf(zo[tid] - tau, 0.0f);
    const float av = ws[WS_SCALE + tid] * P;
    unsigned short h, l;
    split_bf16(av, h, l);
    ((unsigned short*)(ws + WS_AHT))[(size_t)col * 256 + tid] = h;
    ((unsigned short*)(ws + WS_ALT))[(size_t)col * 256 + tid] = l;
    red[tid] = ws[WS_SHIFT + tid] * P;
    __syncthreads();
    for (int off = 128; off > 0; off >>= 1) {
        if (tid < off) red[tid] += red[tid + off];
        __syncthreads();
    }
    if (tid == 0) ws[WS_C2 + col] = red[0] - cut[col];
}

// ---------------------------------------------------------------------------
// k_main: 128x128 tile, 256 thr = 4 waves (2x2 of 64x64). grid (512, 8).
// K-loop: 8 chunks of K=32; per wave 16 ds_read_b128 + 48 MFMA per chunk.
// LDS (40960 B):
//   K-phase (bf16 units): XH@0, XL@5120, BH@10240, BL@15360; rows [*][40] pad.
//   MLP-phase (f32 units): scT@0 [32][132], hT@4224 [32][132],
//     W1T@8448 [32][36], W2T@9600 [16][36], b1@10176 [32].
// ---------------------------------------------------------------------------
template <int ATOMIC>
__global__ __launch_bounds__(256, 3) void k_main(
        const float* __restrict__ x, const float* __restrict__ W1g,
        const float* __restrict__ b1g, const float* __restrict__ W2g,
        const float* __restrict__ twg, float* __restrict__ ws,
        float* __restrict__ out) {
    __shared__ __align__(16) char smem_raw[40960];
    short* sb = (short*)smem_raw;
    float* sf = (float*)smem_raw;

    const int tid  = threadIdx.x;
    const int lane = tid & 63;
    const int wid  = tid >> 6;
    const int lrow = lane & 15;
    const int kgrp = (lane >> 4) * 8;
    const int m0   = (wid >> 1) * 64;
    const int n0   = (wid & 1) * 64;
    const int r0   = blockIdx.x * 128;
    const int c0   = blockIdx.y * 128;

    const unsigned short* AhT = (const unsigned short*)(ws + WS_AHT);
    const unsigned short* AlT = (const unsigned short*)(ws + WS_ALT);
    const float* c2 = ws + WS_C2;

    const int XH = 0, XL = 5120, BHo = 10240, BLo = 15360;        // shorts
    const int SCT = 0, HT = 4224, W1T = 8448, W2T = 9600, B1O = 10176; // floats

    f32x4 acc[4][4];
#pragma unroll
    for (int mi = 0; mi < 4; ++mi)
#pragma unroll
        for (int ni = 0; ni < 4; ++ni)
#pragma unroll
            for (int rr = 0; rr < 4; ++rr) acc[mi][ni][rr] = 0.f;

    // staging assignment: thread -> (row 0..127, k-half 0/16)
    const int r_x = tid >> 1;
    const int k0x = (tid & 1) * 16;
    const float*          xp  = x   + (size_t)(r0 + r_x) * F_DIM + k0x;
    const unsigned short* ahp = AhT + (size_t)(c0 + r_x) * F_DIM + k0x;
    const unsigned short* alp = AlT + (size_t)(c0 + r_x) * F_DIM + k0x;
    short* xh_dst = sb + XH  + r_x * 40 + k0x;
    short* xl_dst = sb + XL  + r_x * 40 + k0x;
    short* bh_dst = sb + BHo + r_x * 40 + k0x;
    short* bl_dst = sb + BLo + r_x * 40 + k0x;

    for (int kc = 0; kc < 256; kc += 32) {
        // stage x chunk: 16 f32 -> bf16 hi/lo
        float fv[16];
        *(float4*)&fv[0]  = *(const float4*)(xp + kc);
        *(float4*)&fv[4]  = *(const float4*)(xp + kc + 4);
        *(float4*)&fv[8]  = *(const float4*)(xp + kc + 8);
        *(float4*)&fv[12] = *(const float4*)(xp + kc + 12);
        bf16x8 xh0, xh1, xl0, xl1;
#pragma unroll
        for (int e = 0; e < 8; ++e) {
            unsigned short h, l;
            split_bf16(fv[e], h, l);
            xh0[e] = (short)h; xl0[e] = (short)l;
        }
#pragma unroll
        for (int e = 0; e < 8; ++e) {
            unsigned short h, l;
            split_bf16(fv[8 + e], h, l);
            xh1[e] = (short)h; xl1[e] = (short)l;
        }
        *(bf16x8*)(xh_dst)     = xh0;
        *(bf16x8*)(xh_dst + 8) = xh1;
        *(bf16x8*)(xl_dst)     = xl0;
        *(bf16x8*)(xl_dst + 8) = xl1;
        // stage A chunk (already bf16, already transposed)
        bf16x8 ahv0 = *(const bf16x8*)(ahp + kc);
        bf16x8 ahv1 = *(const bf16x8*)(ahp + kc + 8);
        bf16x8 alv0 = *(const bf16x8*)(alp + kc);
        bf16x8 alv1 = *(const bf16x8*)(alp + kc + 8);
        *(bf16x8*)(bh_dst)     = ahv0;
        *(bf16x8*)(bh_dst + 8) = ahv1;
        *(bf16x8*)(bl_dst)     = alv0;
        *(bf16x8*)(bl_dst + 8) = alv1;
        __syncthreads();
        // fragments + MFMA
        bf16x8 bh[4], bl[4];
#pragma unroll
        for (int ni = 0; ni < 4; ++ni) {
            const int cb = (n0 + ni * 16 + lrow) * 40 + kgrp;
            bh[ni] = *(const bf16x8*)(sb + BHo + cb);
            bl[ni] = *(const bf16x8*)(sb + BLo + cb);
        }
#pragma unroll
        for (int mi = 0; mi < 4; ++mi) {
            const int rb = (m0 + mi * 16 + lrow) * 40 + kgrp;
            const bf16x8 ah = *(const bf16x8*)(sb + XH + rb);
            const bf16x8 al = *(const bf16x8*)(sb + XL + rb);
#pragma unroll
            for (int ni = 0; ni < 4; ++ni) {
                acc[mi][ni] = __builtin_amdgcn_mfma_f32_16x16x32_bf16(ah, bh[ni], acc[mi][ni], 0, 0, 0);
                acc[mi][ni] = __builtin_amdgcn_mfma_f32_16x16x32_bf16(al, bh[ni], acc[mi][ni], 0, 0, 0);
                acc[mi][ni] = __builtin_amdgcn_mfma_f32_16x16x32_bf16(ah, bl[ni], acc[mi][ni], 0, 0, 0);
            }
        }
        __syncthreads();
    }

    // ---- MLP phase ----
    float c2v[4];
#pragma unroll
    for (int ni = 0; ni < 4; ++ni) c2v[ni] = c2[c0 + n0 + ni * 16 + lrow];

    const int tx = tid & 15, ty = tid >> 4;
    float acc3[8];
#pragma unroll
    for (int j = 0; j < 8; ++j) acc3[j] = 0.f;

    // Fully unrolled: acc[mi][(tt&1)*2+q] must be statically indexed (rule #20).
#pragma unroll
    for (int tt = 0; tt < 4; ++tt) {
        const int gt = blockIdx.y * 4 + tt;
        __syncthreads();   // prior phase's LDS reads done before overwrite
        // score for tree tt -> scT[s][132 r]; owned by waves with matching n-half
        if ((wid & 1) == (tt >> 1)) {
#pragma unroll
            for (int q = 0; q < 2; ++q) {
                const int ni = (tt & 1) * 2 + q;
                const int sl = q * 16 + lrow;
#pragma unroll
                for (int mi = 0; mi < 4; ++mi) {
#pragma unroll
                    for (int rr = 0; rr < 4; ++rr) {
                        const float z = acc[mi][ni][rr] + c2v[ni];
                        sf[SCT + sl * 132 + m0 + mi * 16 + (lane >> 4) * 4 + rr] =
                            1.0f / (1.0f + expf(-z));
                    }
                }
            }
        }
        // stage W1T[j][36] = W1[s][j]
        {
            const float4 v = *(const float4*)&W1g[(size_t)gt * 1024 + tid * 4];
            const int s = tid >> 3, j0 = (tid & 7) * 4;
            sf[W1T + (j0 + 0) * 36 + s] = v.x;
            sf[W1T + (j0 + 1) * 36 + s] = v.y;
            sf[W1T + (j0 + 2) * 36 + s] = v.z;
            sf[W1T + (j0 + 3) * 36 + s] = v.w;
        }
        // stage W2T[o][36] = W2[j][o] * tw[o] / T
        if (tid < 128) {
            const float4 v = *(const float4*)&W2g[(size_t)gt * 512 + tid * 4];
            const int j = tid >> 2, o0 = (tid & 3) * 4;
            const float sc = 1.0f / (float)T_TREES;
            sf[W2T + (o0 + 0) * 36 + j] = v.x * twg[gt * 16 + o0 + 0] * sc;
            sf[W2T + (o0 + 1) * 36 + j] = v.y * twg[gt * 16 + o0 + 1] * sc;
            sf[W2T + (o0 + 2) * 36 + j] = v.z * twg[gt * 16 + o0 + 2] * sc;
            sf[W2T + (o0 + 3) * 36 + j] = v.w * twg[gt * 16 + o0 + 3] * sc;
        }
        if (tid < 32) sf[B1O + tid] = b1g[gt * 32 + tid];
        __syncthreads();
        // GEMM2: h[r][2tx], h[r][2tx+1]
        float a20[8], a21[8];
#pragma unroll
        for (int j = 0; j < 8; ++j) { a20[j] = 0.f; a21[j] = 0.f; }
#pragma unroll
        for (int s4 = 0; s4 < 8; ++s4) {
            const float4 wq0 = *(const float4*)&sf[W1T + (2 * tx) * 36 + s4 * 4];
            const float4 wq1 = *(const float4*)&sf[W1T + (2 * tx + 1) * 36 + s4 * 4];
            const float wa0[4] = {wq0.x, wq0.y, wq0.z, wq0.w};
            const float wa1[4] = {wq1.x, wq1.y, wq1.z, wq1.w};
#pragma unroll
            for (int ss = 0; ss < 4; ++ss) {
                const int s = s4 * 4 + ss;
                const float4 sa0 = *(const float4*)&sf[SCT + s * 132 + ty * 8];
                const float4 sa1 = *(const float4*)&sf[SCT + s * 132 + ty * 8 + 4];
                const float sr[8] = {sa0.x, sa0.y, sa0.z, sa0.w, sa1.x, sa1.y, sa1.z, sa1.w};
#pragma unroll
                for (int j = 0; j < 8; ++j) {
                    a20[j] = fmaf(sr[j], wa0[ss], a20[j]);
                    a21[j] = fmaf(sr[j], wa1[ss], a21[j]);
                }
            }
        }
        const float b1a = sf[B1O + 2 * tx];
        const float b1b = sf[B1O + 2 * tx + 1];
        // hT[j][132 r] (disjoint from scT/W1T/W2T -> no sync before write)
#pragma unroll
        for (int j = 0; j < 8; ++j)
            sf[HT + (2 * tx) * 132 + ty * 8 + j] = fmaxf(a20[j] + b1a, 0.f);
#pragma unroll
        for (int j = 0; j < 8; ++j)
            sf[HT + (2 * tx + 1) * 132 + ty * 8 + j] = fmaxf(a21[j] + b1b, 0.f);
        __syncthreads();
        // GEMM3: o = tx, accumulate across trees
#pragma unroll
        for (int j4 = 0; j4 < 8; ++j4) {
            const float4 wq = *(const float4*)&sf[W2T + tx * 36 + j4 * 4];
            const float wa[4] = {wq.x, wq.y, wq.z, wq.w};
#pragma unroll
            for (int u = 0; u < 4; ++u) {
                const int jj = j4 * 4 + u;
                const float4 h0 = *(const float4*)&sf[HT + jj * 132 + ty * 8];
                const float4 h1 = *(const float4*)&sf[HT + jj * 132 + ty * 8 + 4];
                const float hr[8] = {h0.x, h0.y, h0.z, h0.w, h1.x, h1.y, h1.z, h1.w};
#pragma unroll
                for (int j = 0; j < 8; ++j) acc3[j] = fmaf(hr[j], wa[u], acc3[j]);
            }
        }
    }

    if (ATOMIC) {
#pragma unroll
        for (int j = 0; j < 8; ++j)
            atomicAdd(&out[(size_t)(r0 + ty * 8 + j) * 16 + tx], acc3[j]);
    } else {
        float* pp = ws + WS_PART + (size_t)blockIdx.y * (B_ROWS * 16);
#pragma unroll
        for (int j = 0; j < 8; ++j)
            pp[(size_t)(r0 + ty * 8 + j) * 16 + tx] = acc3[j];
    }
}

__global__ void k_reduce(const float* __restrict__ ws, float* __restrict__ out) {
    const int idx = blockIdx.x * 256 + threadIdx.x;
    float s = ws[WS_BIAS + (idx & 15)];
#pragma unroll
    for (int cb = 0; cb < 8; ++cb) s += ws[WS_PART + (size_t)cb * 1048576 + idx];
    out[idx] = s;
}

__global__ void k_init_out(const float* __restrict__ ws, float* __restrict__ out) {
    const int idx = blockIdx.x * 256 + threadIdx.x;
    out[idx] = ws[WS_BIAS + (idx & 15)];
}

extern "C" void kernel_launch(void* const* d_in, const int* in_sizes, int n_in,
                              void* d_out, int out_size, void* d_ws, size_t ws_size,
                              hipStream_t stream) {
    (void)in_sizes; (void)n_in; (void)out_size;
    const float* x     = (const float*)d_in[0];
    const float* gamma = (const float*)d_in[1];
    const float* beta  = (const float*)d_in[2];
    const float* fsm   = (const float*)d_in[3];
    const float* cut   = (const float*)d_in[4];
    const float* W1    = (const float*)d_in[5];
    const float* b1    = (const float*)d_in[6];
    const float* W2    = (const float*)d_in[7];
    const float* b2    = (const float*)d_in[8];
    const float* tw    = (const float*)d_in[9];
    float* out = (float*)d_out;
    float* ws  = (float*)d_ws;

    // ws guard: never write OOB (clean fail instead of container death)
    if (ws_size < (size_t)WS_FLOATS_ATOMIC * sizeof(float)) return;

    const bool partial = ws_size >= (size_t)WS_FLOATS_PARTIAL * sizeof(float);

    k_zero<<<1, 512, 0, stream>>>(ws);
    k_stats<<<512, 256, 0, stream>>>(x, ws);
    k_finalize<<<1, 256, 0, stream>>>(gamma, beta, b2, tw, ws);
    k_sparsemax<<<1024, 256, 0, stream>>>(fsm, cut, ws);
    if (partial) {
        k_main<0><<<dim3(512, 8), 256, 0, stream>>>(x, W1, b1, W2, tw, ws, out);
        k_reduce<<<4096, 256, 0, stream>>>(ws, out);
    } else {
        k_init_out<<<4096, 256, 0, stream>>>(ws, out);
        k_main<1><<<dim3(512, 8), 256, 0, stream>>>(x, W1, b1, W2, tw, ws, out);
    }
}